// Round 4
// baseline (170.879 us; speedup 1.0000x reference)
//
#include <hip/hip_runtime.h>
#include <math.h>

// MAM dense: C[m,n] = max_k(A[m,k]*W[n,k]) + min_k(A[m,k]*W[n,k]) + bias[n]
// A: [M,K] fp32, W: [N,K] fp32 (torch layout), C: [M,N]
//
// R17 = R16 with the packed multiply returned to the compiler.
// R16 post-mortem: conflicts 5.1M->885K but dur unchanged (131->130) ->
// conflicts were never the gate (per-CU they are ~5-8us). VALUBusy is
// 4-SIMD-aggregated: R16 = 70%/400% = 17.6% per SIMD; all pipes (VALU
// ~23us, DS ~45us, HBM ~6us) well under the 130us wall -> dependency-
// stall-bound. Root cause of the R13(103us)->R15/16(130us) regression:
// the asm v_pk_mul_f32 feeds the very next asm max3 (back-to-back asm
// triple in source order) leaving ~4cy dependent latency exposed per
// element; R13's muls were compiler IR and got hoisted across the 64
// independent accumulator updates. Fix: f32x2 p = a*b (LLVM gfx90a+
// selects v_pk_mul_f32 for v2f32 fmul) -> schedulable again, keeping
// the 3-instr-per-k-pair stream. Worst case (scalarized): R13's mix
// with a conflict-free layout = no worse than 103us.

#define TS 64
#define BK 16
#define RSF 156              // bumped row stride: 7*20 + 16 = 156 floats
#define STRIPF (8 * RSF)     // (BK/2) rows per strip = 1248 floats

typedef __attribute__((ext_vector_type(2))) float f32x2;
typedef __attribute__((ext_vector_type(4))) float f32x4;

__device__ __forceinline__ f32x2 lo2(f32x4 v) { return __builtin_shufflevector(v, v, 0, 1); }
__device__ __forceinline__ f32x2 hi2(f32x4 v) { return __builtin_shufflevector(v, v, 2, 3); }

__device__ __forceinline__ void mam_upd_pk(float& mx, float& mn, f32x2 a, f32x2 b) {
    f32x2 p = a * b;   // v_pk_mul_f32 via compiler IR -> freely schedulable
    asm("v_max3_f32 %0, %1, %2, %0" : "+v"(mx) : "v"(p.x), "v"(p.y));
    asm("v_min3_f32 %0, %1, %2, %0" : "+v"(mn) : "v"(p.x), "v"(p.y));
}

__global__
__attribute__((amdgpu_flat_work_group_size(256, 256)))
__attribute__((amdgpu_waves_per_eu(2, 2)))
void mam_sk(
    const float* __restrict__ A, const float* __restrict__ W,
    const float* __restrict__ bias, float* __restrict__ C,
    int M, int N, int K)
{
    // union: [0..4*STRIPF) sA strips, [4*STRIPF..8*STRIPF) sW strips;
    // after the main loop (barrier) the same memory holds cmx/cmn (64x64 each;
    // 8192 floats <= 8*STRIPF = 9984).
    __shared__ __align__(16) float smem[8 * STRIPF];   // 39936 B
    float* cmx = smem;
    float* cmn = smem + TS * TS;

    const int t    = threadIdx.x;
    const int w    = t >> 6;        // wave id == k-group
    const int lane = t & 63;
    const int ty   = lane >> 3;     // m micro thread (8 rows)
    const int tx   = lane & 7;      // n micro thread (8 cols)
    const int m0   = blockIdx.y * TS;
    const int n0   = blockIdx.x * TS;
    const int kc   = K >> 2;        // 256 k per wave
    const int kb0  = w * kc;

    const int sr = lane >> 2;       // staging row 0..15
    const int sc = lane & 3;        // staging k-quad 0..3

    float* sAw = smem + (size_t)w * STRIPF;          // this wave's A strip
    float* sWw = smem + (size_t)(4 + w) * STRIPF;    // this wave's W strip

    const float* Ap = A + (size_t)(m0 + sr) * K + kb0 + sc * 4;
    const float* Wp = W + (size_t)(n0 + sr) * K + kb0 + sc * 4;

    float mx[8][8], mn[8][8];
#pragma unroll
    for (int i = 0; i < 8; ++i)
#pragma unroll
        for (int j = 0; j < 8; ++j) {
            mx[i][j] = -INFINITY;
            mn[i][j] =  INFINITY;
        }

    float4 ra[4], rw[4];
#pragma unroll
    for (int q = 0; q < 4; ++q) {
        ra[q] = *(const float4*)(Ap + (size_t)q * 16 * K);
        rw[q] = *(const float4*)(Wp + (size_t)q * 16 * K);
    }
    Ap += BK;
    Wp += BK;

    // bumped pair offset for this lane's staging rows (q adds 40 floats):
    // m = sr + 16q -> pair offset 20*((sr>>3) + 2q) + 2*(sr&7)
    const int mo = 20 * (sr >> 3) + 2 * (sr & 7);

    const int nStages = kc / BK;    // 16
    for (int s = 0; s < nStages; ++s) {
        // scatter current stage into this wave's strip, k-pair interleaved
        // with the stride-20 bump; float4 (k0..k3) for row m -> (x,y) to
        // kp-row sc*2, (z,w) to kp-row sc*2+1.
        // (no barrier: strip is wave-private; same-wave DS ops are ordered)
#pragma unroll
        for (int q = 0; q < 4; ++q) {
            const int po = mo + 40 * q;
            *(float2*)&sAw[(sc * 2 + 0) * RSF + po] = make_float2(ra[q].x, ra[q].y);
            *(float2*)&sAw[(sc * 2 + 1) * RSF + po] = make_float2(ra[q].z, ra[q].w);
            *(float2*)&sWw[(sc * 2 + 0) * RSF + po] = make_float2(rw[q].x, rw[q].y);
            *(float2*)&sWw[(sc * 2 + 1) * RSF + po] = make_float2(rw[q].z, rw[q].w);
        }
        // prefetch next stage while computing this one
        if (s + 1 < nStages) {
#pragma unroll
            for (int q = 0; q < 4; ++q) {
                ra[q] = *(const float4*)(Ap + (size_t)q * 16 * K);
                rw[q] = *(const float4*)(Wp + (size_t)q * 16 * K);
            }
            Ap += BK;
            Wp += BK;
        }

#pragma unroll
        for (int kp = 0; kp < BK / 2; ++kp) {
            const float* rA = sAw + kp * RSF + ty * 20;
            const float* rW = sWw + kp * RSF + tx * 20;
            f32x4 A0 = *(const f32x4*)(rA + 0);
            f32x4 A1 = *(const f32x4*)(rA + 4);
            f32x4 A2 = *(const f32x4*)(rA + 8);
            f32x4 A3 = *(const f32x4*)(rA + 12);
            f32x4 W0 = *(const f32x4*)(rW + 0);
            f32x4 W1 = *(const f32x4*)(rW + 4);
            f32x4 W2 = *(const f32x4*)(rW + 8);
            f32x4 W3 = *(const f32x4*)(rW + 12);

            f32x2 av[8] = {lo2(A0), hi2(A0), lo2(A1), hi2(A1),
                           lo2(A2), hi2(A2), lo2(A3), hi2(A3)};
            f32x2 bv[8] = {lo2(W0), hi2(W0), lo2(W1), hi2(W1),
                           lo2(W2), hi2(W2), lo2(W3), hi2(W3)};

#pragma unroll
            for (int i = 0; i < 8; ++i)
#pragma unroll
                for (int j = 0; j < 8; ++j)
                    mam_upd_pk(mx[i][j], mn[i][j], av[i], bv[j]);
        }
    }

    // strips now dead; cmx/cmn overlap them -> drain all waves first
    __syncthreads();

    // ---- cross-wave combine: sequential merge rounds through LDS ----
    for (int rnd = 0; rnd < 4; ++rnd) {
        if (w == rnd) {
#pragma unroll
            for (int i = 0; i < 8; ++i)
#pragma unroll
                for (int j = 0; j < 8; ++j) {
                    const int idx = (ty * 8 + i) * TS + tx * 8 + j;
                    if (rnd == 0) {
                        cmx[idx] = mx[i][j];
                        cmn[idx] = mn[i][j];
                    } else {
                        cmx[idx] = fmaxf(cmx[idx], mx[i][j]);
                        cmn[idx] = fminf(cmn[idx], mn[i][j]);
                    }
                }
        }
        __syncthreads();
    }

    // ---- bias + store: wave w writes micro-rows i = {2w, 2w+1} ----
    float4 blo = *(const float4*)(bias + n0 + tx * 8);
    float4 bhi = *(const float4*)(bias + n0 + tx * 8 + 4);
#pragma unroll
    for (int i2 = 0; i2 < 2; ++i2) {
        const int i   = w * 2 + i2;
        const int row = ty * 8 + i;
        const int idx = row * TS + tx * 8;
        float4 o0, o1;
        o0.x = cmx[idx + 0] + cmn[idx + 0] + blo.x;
        o0.y = cmx[idx + 1] + cmn[idx + 1] + blo.y;
        o0.z = cmx[idx + 2] + cmn[idx + 2] + blo.z;
        o0.w = cmx[idx + 3] + cmn[idx + 3] + blo.w;
        o1.x = cmx[idx + 4] + cmn[idx + 4] + bhi.x;
        o1.y = cmx[idx + 5] + cmn[idx + 5] + bhi.y;
        o1.z = cmx[idx + 6] + cmn[idx + 6] + bhi.z;
        o1.w = cmx[idx + 7] + cmn[idx + 7] + bhi.w;
        float4* p = (float4*)(C + (size_t)(m0 + row) * N + n0 + tx * 8);
        p[0] = o0;
        p[1] = o1;
    }
}

// ---- fallback (proven R2 kernel) for shapes the fast path can't take ----
#define BM 64
#define BN 64
#define FBK 32
#define LDSW 68

__device__ __forceinline__ void mam_upd_fb(float& mx, float& mn, float p0, float p1) {
    float nmx, nmn;
    asm("v_max3_f32 %0, %1, %2, %3" : "=v"(nmx) : "v"(p0), "v"(p1), "v"(mx));
    asm("v_min3_f32 %0, %1, %2, %3" : "=v"(nmn) : "v"(p0), "v"(p1), "v"(mn));
    mx = nmx;
    mn = nmn;
}

__global__ __launch_bounds__(256) void mam_fallback(
    const float* __restrict__ A, const float* __restrict__ W,
    const float* __restrict__ bias, float* __restrict__ C,
    int M, int N, int K)
{
    __shared__ float Asf[FBK][LDSW];
    __shared__ float Wsf[FBK][LDSW];

    const int t  = threadIdx.x;
    const int tx = t & 15;
    const int ty = t >> 4;
    const int m0 = blockIdx.y * BM;
    const int n0 = blockIdx.x * BN;
    const int r  = t >> 3;
    const int kq = t & 7;

    const float* Aptr = A + (size_t)(m0 + r) * K + kq * 4;
    const float* Wptr = W + (size_t)(n0 + r) * K + kq * 4;

    float vmax[4][4], vmin[4][4];
#pragma unroll
    for (int i = 0; i < 4; ++i)
#pragma unroll
        for (int j = 0; j < 4; ++j) {
            vmax[i][j] = -INFINITY;
            vmin[i][j] =  INFINITY;
        }

    for (int k0 = 0; k0 < K; k0 += FBK) {
        float4 a0 = *(const float4*)(Aptr);
        float4 a1 = *(const float4*)(Aptr + (size_t)32 * K);
        float4 w0 = *(const float4*)(Wptr);
        float4 w1 = *(const float4*)(Wptr + (size_t)32 * K);
        Aptr += FBK;
        Wptr += FBK;

        const int kk = kq * 4;
        Asf[kk + 0][r]      = a0.x;
        Asf[kk + 1][r]      = a0.y;
        Asf[kk + 2][r]      = a0.z;
        Asf[kk + 3][r]      = a0.w;
        Asf[kk + 0][r + 32] = a1.x;
        Asf[kk + 1][r + 32] = a1.y;
        Asf[kk + 2][r + 32] = a1.z;
        Asf[kk + 3][r + 32] = a1.w;

        Wsf[kk + 0][r]      = w0.x;
        Wsf[kk + 1][r]      = w0.y;
        Wsf[kk + 2][r]      = w0.z;
        Wsf[kk + 3][r]      = w0.w;
        Wsf[kk + 0][r + 32] = w1.x;
        Wsf[kk + 1][r + 32] = w1.y;
        Wsf[kk + 2][r + 32] = w1.z;
        Wsf[kk + 3][r + 32] = w1.w;

        __syncthreads();

#pragma unroll
        for (int k = 0; k < FBK; k += 2) {
            float4 ta0 = *(const float4*)&Asf[k    ][ty * 4];
            float4 ta1 = *(const float4*)&Asf[k + 1][ty * 4];
            float4 tb0 = *(const float4*)&Wsf[k    ][tx * 4];
            float4 tb1 = *(const float4*)&Wsf[k + 1][tx * 4];

            float a0v[4] = {ta0.x, ta0.y, ta0.z, ta0.w};
            float a1v[4] = {ta1.x, ta1.y, ta1.z, ta1.w};
            float b0v[4] = {tb0.x, tb0.y, tb0.z, tb0.w};
            float b1v[4] = {tb1.x, tb1.y, tb1.z, tb1.w};

#pragma unroll
            for (int i = 0; i < 4; ++i)
#pragma unroll
                for (int j = 0; j < 4; ++j) {
                    float p0 = a0v[i] * b0v[j];
                    float p1 = a1v[i] * b1v[j];
                    mam_upd_fb(vmax[i][j], vmin[i][j], p0, p1);
                }
        }
        __syncthreads();
    }

    float4 bv = *(const float4*)(bias + n0 + tx * 4);
#pragma unroll
    for (int i = 0; i < 4; ++i) {
        float4 o;
        o.x = vmax[i][0] + vmin[i][0] + bv.x;
        o.y = vmax[i][1] + vmin[i][1] + bv.y;
        o.z = vmax[i][2] + vmin[i][2] + bv.z;
        o.w = vmax[i][3] + vmin[i][3] + bv.w;
        *(float4*)(C + (size_t)(m0 + ty * 4 + i) * N + n0 + tx * 4) = o;
    }
}

extern "C" void kernel_launch(void* const* d_in, const int* in_sizes, int n_in,
                              void* d_out, int out_size, void* d_ws, size_t ws_size,
                              hipStream_t stream) {
    const float* x    = (const float*)d_in[0];
    const float* w    = (const float*)d_in[1];
    const float* bias = (const float*)d_in[2];
    float* out = (float*)d_out;

    const int N = in_sizes[2];
    const int K = in_sizes[1] / N;
    const int M = in_sizes[0] / K;

    const bool fast_ok = (K % (4 * BK) == 0) && (M % TS == 0) && (N % TS == 0);

    if (fast_ok) {
        dim3 grid(N / TS, M / TS);   // (16, 32) = 512 blocks
        mam_sk<<<grid, 256, 0, stream>>>(x, w, bias, out, M, N, K);
    } else {
        dim3 grid(N / BN, M / BM);
        mam_fallback<<<grid, 256, 0, stream>>>(x, w, bias, out, M, N, K);
    }
}

// Round 7
// 158.397 us; speedup vs baseline: 1.0788x; 1.0788x over previous
//
#include <hip/hip_runtime.h>
#include <math.h>

// MAM dense: C[m,n] = max_k(A[m,k]*W[n,k]) + min_k(A[m,k]*W[n,k]) + bias[n]
// A: [M,K] fp32, W: [N,K] fp32 (torch layout), C: [M,N]
//
// R20 = R18/R19 with waves_per_eu relaxed (4,4)->(3,4).
// R18 and R19 (identical source) both died with "container failed twice";
// R14's lone infra failure resubmitted cleanly, so suspect the binary:
// waves_per_eu(4,4) imposes a hard 128-VGPR cap while demand is ~127-140
// (64 accums tied "+v" in inline asm -- unspillable at the asm site --
// plus 6 even-aligned f32x4 LDS tuples + 2 float4 staging tuples needing
// contiguous quads). RA can fail outright under that cap. (3,4) gives the
// allocator a 168-reg budget: <=128 regs still yields 4 waves/SIMD; worst
// case 3 waves/SIMD = 12 waves/CU = 1.5x baseline occupancy.
//
// Underlying theory (R17 post-mortem, unchanged): all pipes <=53% of the
// 103-130us wall (VALU floor 54.6us, DS ~48us/CU, HBM 6us) => latency-
// bound at 2 waves/SIMD. Fix: 64x32 tile, 8x4 micro => accum 64 VGPRs,
// no register prefetch (TLP covers stage-top global latency), scalar muls
// (proven R13 form). Conflict-free bumped strips: A stride-20
// (R16-verified), W stride-12 (12g mod 32 = 8 disjoint bank quads).
// Predicted: dur 103 -> 75-95us, Occupancy 18->27-35%, VGPR<=168 no spill.

#define TSM 64               // m tile
#define TSN 32               // n tile
#define BK 16                // k per stage
#define ARS 156              // A row stride: 7*20 + 16
#define WRS 92               // W row stride: 7*12 + 8
#define ASTRIP (8 * ARS)     // 1248 floats
#define WSTRIP (8 * WRS)     // 736 floats
#define WAVEF (ASTRIP + WSTRIP)  // 1984 floats per wave

typedef __attribute__((ext_vector_type(4))) float f32x4;

__device__ __forceinline__ void mam_upd(float& mx, float& mn, float p0, float p1) {
    asm("v_max3_f32 %0, %1, %2, %0" : "+v"(mx) : "v"(p0), "v"(p1));
    asm("v_min3_f32 %0, %1, %2, %0" : "+v"(mn) : "v"(p0), "v"(p1));
}

__global__
__attribute__((amdgpu_flat_work_group_size(256, 256)))
__attribute__((amdgpu_waves_per_eu(3, 4)))
void mam_sk(
    const float* __restrict__ A, const float* __restrict__ W,
    const float* __restrict__ bias, float* __restrict__ C,
    int M, int N, int K)
{
    // 4 wave strips (A+W interleaved per wave) = 7936 floats = 31744 B.
    // After the main loop (barrier) the same memory holds cmx/cmn
    // (64x32 each = 4096 floats <= 7936).
    __shared__ __align__(16) float smem[4 * WAVEF];
    float* cmx = smem;
    float* cmn = smem + TSM * TSN;

    const int t    = threadIdx.x;
    const int w    = t >> 6;        // wave id == k-group
    const int lane = t & 63;
    const int ty   = lane >> 3;     // m micro group (8 rows each)
    const int tx   = lane & 7;      // n micro group (4 cols each)
    const int m0   = blockIdx.y * TSM;
    const int n0   = blockIdx.x * TSN;
    const int kc   = K >> 2;        // 256 k per wave
    const int kb0  = w * kc;

    const int sr = lane >> 2;       // staging row 0..15
    const int sc = lane & 3;        // staging k-quad 0..3

    float* sAw = smem + w * WAVEF;
    float* sWw = sAw + ASTRIP;

    const float* Ap = A + (size_t)(m0 + sr) * K + kb0 + sc * 4;
    const float* Wp = W + (size_t)(n0 + sr) * K + kb0 + sc * 4;

    float mx[8][4], mn[8][4];
#pragma unroll
    for (int i = 0; i < 8; ++i)
#pragma unroll
        for (int j = 0; j < 4; ++j) {
            mx[i][j] = -INFINITY;
            mn[i][j] =  INFINITY;
        }

    // bumped pair offsets for this lane's staging rows:
    // A row m = sr+16q -> 20*((sr>>3)+2q) + 2*(sr&7) = moA + 40q
    // W row n = sr+16q -> 12*((sr>>2)+4q) + 2*(sr&3) = moW + 48q
    const int moA = 20 * (sr >> 3) + 2 * (sr & 7);
    const int moW = 12 * (sr >> 2) + 2 * (sr & 3);

    const int nStages = kc / BK;    // 16
    for (int s = 0; s < nStages; ++s) {
        // ---- load this stage (no register prefetch; TLP hides latency) ----
        float4 ra[4], rw[2];
#pragma unroll
        for (int q = 0; q < 4; ++q)
            ra[q] = *(const float4*)(Ap + (size_t)q * 16 * K);
#pragma unroll
        for (int q = 0; q < 2; ++q)
            rw[q] = *(const float4*)(Wp + (size_t)q * 16 * K);
        Ap += BK;
        Wp += BK;

        // ---- scatter into this wave's strip, k-pair interleaved+bumped ----
        // float4 (k0..k3): (x,y) -> kp-row sc*2, (z,w) -> kp-row sc*2+1.
        // (no barrier: strip is wave-private; same-wave DS ops are ordered)
#pragma unroll
        for (int q = 0; q < 4; ++q) {
            const int po = moA + 40 * q;
            *(float2*)&sAw[(sc * 2 + 0) * ARS + po] = make_float2(ra[q].x, ra[q].y);
            *(float2*)&sAw[(sc * 2 + 1) * ARS + po] = make_float2(ra[q].z, ra[q].w);
        }
#pragma unroll
        for (int q = 0; q < 2; ++q) {
            const int po = moW + 48 * q;
            *(float2*)&sWw[(sc * 2 + 0) * WRS + po] = make_float2(rw[q].x, rw[q].y);
            *(float2*)&sWw[(sc * 2 + 1) * WRS + po] = make_float2(rw[q].z, rw[q].w);
        }

        // ---- compute: 8 k-pairs, 8x4 micro-tile, scalar muls ----
#pragma unroll
        for (int kp = 0; kp < BK / 2; ++kp) {
            const float* rA = sAw + kp * ARS + ty * 20;
            const float* rW = sWw + kp * WRS + tx * 12;
            f32x4 A0 = *(const f32x4*)(rA + 0);
            f32x4 A1 = *(const f32x4*)(rA + 4);
            f32x4 A2 = *(const f32x4*)(rA + 8);
            f32x4 A3 = *(const f32x4*)(rA + 12);
            f32x4 W0 = *(const f32x4*)(rW + 0);
            f32x4 W1 = *(const f32x4*)(rW + 4);

            float a0[8] = {A0.x, A0.z, A1.x, A1.z, A2.x, A2.z, A3.x, A3.z};
            float a1[8] = {A0.y, A0.w, A1.y, A1.w, A2.y, A2.w, A3.y, A3.w};
            float b0[4] = {W0.x, W0.z, W1.x, W1.z};
            float b1[4] = {W0.y, W0.w, W1.y, W1.w};

#pragma unroll
            for (int i = 0; i < 8; ++i)
#pragma unroll
                for (int j = 0; j < 4; ++j) {
                    float p0 = a0[i] * b0[j];
                    float p1 = a1[i] * b1[j];
                    mam_upd(mx[i][j], mn[i][j], p0, p1);
                }
        }
    }

    // strips now dead; cmx/cmn overlap them -> drain all waves first
    __syncthreads();

    // ---- cross-wave combine: sequential merge rounds through LDS ----
    for (int rnd = 0; rnd < 4; ++rnd) {
        if (w == rnd) {
#pragma unroll
            for (int i = 0; i < 8; ++i)
#pragma unroll
                for (int j = 0; j < 4; ++j) {
                    const int idx = (ty * 8 + i) * TSN + tx * 4 + j;
                    if (rnd == 0) {
                        cmx[idx] = mx[i][j];
                        cmn[idx] = mn[i][j];
                    } else {
                        cmx[idx] = fmaxf(cmx[idx], mx[i][j]);
                        cmn[idx] = fminf(cmn[idx], mn[i][j]);
                    }
                }
        }
        __syncthreads();
    }

    // ---- bias + store: thread t -> row t>>2, col quad t&3 (8 cols) ----
    {
        const int row = t >> 2;
        const int cq  = t & 3;
        const int col = cq * 8;
        float4 blo = *(const float4*)(bias + n0 + col);
        float4 bhi = *(const float4*)(bias + n0 + col + 4);
        const int idx = row * TSN + col;
        float4 o0, o1;
        o0.x = cmx[idx + 0] + cmn[idx + 0] + blo.x;
        o0.y = cmx[idx + 1] + cmn[idx + 1] + blo.y;
        o0.z = cmx[idx + 2] + cmn[idx + 2] + blo.z;
        o0.w = cmx[idx + 3] + cmn[idx + 3] + blo.w;
        o1.x = cmx[idx + 4] + cmn[idx + 4] + bhi.x;
        o1.y = cmx[idx + 5] + cmn[idx + 5] + bhi.y;
        o1.z = cmx[idx + 6] + cmn[idx + 6] + bhi.z;
        o1.w = cmx[idx + 7] + cmn[idx + 7] + bhi.w;
        float4* p = (float4*)(C + (size_t)(m0 + row) * N + n0 + col);
        p[0] = o0;
        p[1] = o1;
    }
}

// ---- fallback (proven R2 kernel) for shapes the fast path can't take ----
#define BM 64
#define BN 64
#define FBK 32
#define LDSW 68

__device__ __forceinline__ void mam_upd_fb(float& mx, float& mn, float p0, float p1) {
    float nmx, nmn;
    asm("v_max3_f32 %0, %1, %2, %3" : "=v"(nmx) : "v"(p0), "v"(p1), "v"(mx));
    asm("v_min3_f32 %0, %1, %2, %3" : "=v"(nmn) : "v"(p0), "v"(p1), "v"(mn));
    mx = nmx;
    mn = nmn;
}

__global__ __launch_bounds__(256) void mam_fallback(
    const float* __restrict__ A, const float* __restrict__ W,
    const float* __restrict__ bias, float* __restrict__ C,
    int M, int N, int K)
{
    __shared__ float Asf[FBK][LDSW];
    __shared__ float Wsf[FBK][LDSW];

    const int t  = threadIdx.x;
    const int tx = t & 15;
    const int ty = t >> 4;
    const int m0 = blockIdx.y * BM;
    const int n0 = blockIdx.x * BN;
    const int r  = t >> 3;
    const int kq = t & 7;

    const float* Aptr = A + (size_t)(m0 + r) * K + kq * 4;
    const float* Wptr = W + (size_t)(n0 + r) * K + kq * 4;

    float vmax[4][4], vmin[4][4];
#pragma unroll
    for (int i = 0; i < 4; ++i)
#pragma unroll
        for (int j = 0; j < 4; ++j) {
            vmax[i][j] = -INFINITY;
            vmin[i][j] =  INFINITY;
        }

    for (int k0 = 0; k0 < K; k0 += FBK) {
        float4 a0 = *(const float4*)(Aptr);
        float4 a1 = *(const float4*)(Aptr + (size_t)32 * K);
        float4 w0 = *(const float4*)(Wptr);
        float4 w1 = *(const float4*)(Wptr + (size_t)32 * K);
        Aptr += FBK;
        Wptr += FBK;

        const int kk = kq * 4;
        Asf[kk + 0][r]      = a0.x;
        Asf[kk + 1][r]      = a0.y;
        Asf[kk + 2][r]      = a0.z;
        Asf[kk + 3][r]      = a0.w;
        Asf[kk + 0][r + 32] = a1.x;
        Asf[kk + 1][r + 32] = a1.y;
        Asf[kk + 2][r + 32] = a1.z;
        Asf[kk + 3][r + 32] = a1.w;

        Wsf[kk + 0][r]      = w0.x;
        Wsf[kk + 1][r]      = w0.y;
        Wsf[kk + 2][r]      = w0.z;
        Wsf[kk + 3][r]      = w0.w;
        Wsf[kk + 0][r + 32] = w1.x;
        Wsf[kk + 1][r + 32] = w1.y;
        Wsf[kk + 2][r + 32] = w1.z;
        Wsf[kk + 3][r + 32] = w1.w;

        __syncthreads();

#pragma unroll
        for (int k = 0; k < FBK; k += 2) {
            float4 ta0 = *(const float4*)&Asf[k    ][ty * 4];
            float4 ta1 = *(const float4*)&Asf[k + 1][ty * 4];
            float4 tb0 = *(const float4*)&Wsf[k    ][tx * 4];
            float4 tb1 = *(const float4*)&Wsf[k + 1][tx * 4];

            float a0v[4] = {ta0.x, ta0.y, ta0.z, ta0.w};
            float a1v[4] = {ta1.x, ta1.y, ta1.z, ta1.w};
            float b0v[4] = {tb0.x, tb0.y, tb0.z, tb0.w};
            float b1v[4] = {tb1.x, tb1.y, tb1.z, tb1.w};

#pragma unroll
            for (int i = 0; i < 4; ++i)
#pragma unroll
                for (int j = 0; j < 4; ++j) {
                    float p0 = a0v[i] * b0v[j];
                    float p1 = a1v[i] * b1v[j];
                    mam_upd_fb(vmax[i][j], vmin[i][j], p0, p1);
                }
        }
        __syncthreads();
    }

    float4 bv = *(const float4*)(bias + n0 + tx * 4);
#pragma unroll
    for (int i = 0; i < 4; ++i) {
        float4 o;
        o.x = vmax[i][0] + vmin[i][0] + bv.x;
        o.y = vmax[i][1] + vmin[i][1] + bv.y;
        o.z = vmax[i][2] + vmin[i][2] + bv.z;
        o.w = vmax[i][3] + vmin[i][3] + bv.w;
        *(float4*)(C + (size_t)(m0 + ty * 4 + i) * N + n0 + tx * 4) = o;
    }
}

extern "C" void kernel_launch(void* const* d_in, const int* in_sizes, int n_in,
                              void* d_out, int out_size, void* d_ws, size_t ws_size,
                              hipStream_t stream) {
    const float* x    = (const float*)d_in[0];
    const float* w    = (const float*)d_in[1];
    const float* bias = (const float*)d_in[2];
    float* out = (float*)d_out;

    const int N = in_sizes[2];
    const int K = in_sizes[1] / N;
    const int M = in_sizes[0] / K;

    const bool fast_ok = (K % (4 * BK) == 0) && (M % TSM == 0) && (N % TSN == 0);

    if (fast_ok) {
        dim3 grid(N / TSN, M / TSM);   // (32, 32) = 1024 blocks
        mam_sk<<<grid, 256, 0, stream>>>(x, w, bias, out, M, N, K);
    } else {
        dim3 grid(N / BN, M / BM);
        mam_fallback<<<grid, 256, 0, stream>>>(x, w, bias, out, M, N, K);
    }
}

// Round 8
// 156.682 us; speedup vs baseline: 1.0906x; 1.0109x over previous
//
#include <hip/hip_runtime.h>
#include <math.h>

// MAM dense: C[m,n] = max_k(A[m,k]*W[n,k]) + min_k(A[m,k]*W[n,k]) + bias[n]
// A: [M,K] fp32, W: [N,K] fp32 (torch layout), C: [M,N]
//
// R21 = R20 + restored register prefetch (R13's T14 pipeline).
// R20 post-mortem: occupancy fix worked (33%, 16 waves/CU; VGPR=52 --
// accums homed in unified-file AGPR half, ~116/168 regs), VALU issue
// exactly R13's (no inflation), conflicts 311K. But dur=112us > R13's 103:
// R20 loads each stage then vmcnt(0)-drains IMMEDIATELY -> 16 exposed
// ~600-900cy HBM round-trips per wave; and the 8x4 micro raised DS-read
// demand 1.5x (DS pipe ~69us/CU = 62% busy, now the top pipe). Pipe floor
// ~69us, measured 112 -> ~43us exposed latency. Fix: per stage, scatter
// the already-loaded regs, then issue NEXT stage's loads BEFORE the
// 2048cy compute (single reg buffer; compiler orders the WAR on ra/rw).
// Cost +24 arch VGPR -> ~140/168, >=3 waves/SIMD (12 waves/CU).
// Predicted: dur 112 -> 85-95us, VGPR 52->~80, VALUBusy 111->130-150.

#define TSM 64               // m tile
#define TSN 32               // n tile
#define BK 16                // k per stage
#define ARS 156              // A row stride: 7*20 + 16
#define WRS 92               // W row stride: 7*12 + 8
#define ASTRIP (8 * ARS)     // 1248 floats
#define WSTRIP (8 * WRS)     // 736 floats
#define WAVEF (ASTRIP + WSTRIP)  // 1984 floats per wave

typedef __attribute__((ext_vector_type(4))) float f32x4;

__device__ __forceinline__ void mam_upd(float& mx, float& mn, float p0, float p1) {
    asm("v_max3_f32 %0, %1, %2, %0" : "+v"(mx) : "v"(p0), "v"(p1));
    asm("v_min3_f32 %0, %1, %2, %0" : "+v"(mn) : "v"(p0), "v"(p1));
}

__global__
__attribute__((amdgpu_flat_work_group_size(256, 256)))
__attribute__((amdgpu_waves_per_eu(3, 4)))
void mam_sk(
    const float* __restrict__ A, const float* __restrict__ W,
    const float* __restrict__ bias, float* __restrict__ C,
    int M, int N, int K)
{
    // 4 wave strips (A+W interleaved per wave) = 7936 floats = 31744 B.
    // After the main loop (barrier) the same memory holds cmx/cmn
    // (64x32 each = 4096 floats <= 7936).
    __shared__ __align__(16) float smem[4 * WAVEF];
    float* cmx = smem;
    float* cmn = smem + TSM * TSN;

    const int t    = threadIdx.x;
    const int w    = t >> 6;        // wave id == k-group
    const int lane = t & 63;
    const int ty   = lane >> 3;     // m micro group (8 rows each)
    const int tx   = lane & 7;      // n micro group (4 cols each)
    const int m0   = blockIdx.y * TSM;
    const int n0   = blockIdx.x * TSN;
    const int kc   = K >> 2;        // 256 k per wave
    const int kb0  = w * kc;

    const int sr = lane >> 2;       // staging row 0..15
    const int sc = lane & 3;        // staging k-quad 0..3

    float* sAw = smem + w * WAVEF;
    float* sWw = sAw + ASTRIP;

    const float* Ap = A + (size_t)(m0 + sr) * K + kb0 + sc * 4;
    const float* Wp = W + (size_t)(n0 + sr) * K + kb0 + sc * 4;

    float mx[8][4], mn[8][4];
#pragma unroll
    for (int i = 0; i < 8; ++i)
#pragma unroll
        for (int j = 0; j < 4; ++j) {
            mx[i][j] = -INFINITY;
            mn[i][j] =  INFINITY;
        }

    // bumped pair offsets for this lane's staging rows:
    // A row m = sr+16q -> 20*((sr>>3)+2q) + 2*(sr&7) = moA + 40q
    // W row n = sr+16q -> 12*((sr>>2)+4q) + 2*(sr&3) = moW + 48q
    const int moA = 20 * (sr >> 3) + 2 * (sr & 7);
    const int moW = 12 * (sr >> 2) + 2 * (sr & 3);

    // ---- prologue: load stage 0 ----
    float4 ra[4], rw[2];
#pragma unroll
    for (int q = 0; q < 4; ++q)
        ra[q] = *(const float4*)(Ap + (size_t)q * 16 * K);
#pragma unroll
    for (int q = 0; q < 2; ++q)
        rw[q] = *(const float4*)(Wp + (size_t)q * 16 * K);
    Ap += BK;
    Wp += BK;

    const int nStages = kc / BK;    // 16
    for (int s = 0; s < nStages; ++s) {
        // ---- scatter current stage (regs -> strip), k-pair interleaved ----
        // float4 (k0..k3): (x,y) -> kp-row sc*2, (z,w) -> kp-row sc*2+1.
        // (no barrier: strip is wave-private; same-wave DS ops are ordered)
#pragma unroll
        for (int q = 0; q < 4; ++q) {
            const int po = moA + 40 * q;
            *(float2*)&sAw[(sc * 2 + 0) * ARS + po] = make_float2(ra[q].x, ra[q].y);
            *(float2*)&sAw[(sc * 2 + 1) * ARS + po] = make_float2(ra[q].z, ra[q].w);
        }
#pragma unroll
        for (int q = 0; q < 2; ++q) {
            const int po = moW + 48 * q;
            *(float2*)&sWw[(sc * 2 + 0) * WRS + po] = make_float2(rw[q].x, rw[q].y);
            *(float2*)&sWw[(sc * 2 + 1) * WRS + po] = make_float2(rw[q].z, rw[q].w);
        }

        // ---- issue next stage's loads BEFORE compute (T14) ----
        // ds_write consumed ra/rw at issue; loads redefine them afterwards
        // (WAR ordered by compiler); HBM latency hides under ~2048cy compute.
        if (s + 1 < nStages) {
#pragma unroll
            for (int q = 0; q < 4; ++q)
                ra[q] = *(const float4*)(Ap + (size_t)q * 16 * K);
#pragma unroll
            for (int q = 0; q < 2; ++q)
                rw[q] = *(const float4*)(Wp + (size_t)q * 16 * K);
            Ap += BK;
            Wp += BK;
        }

        // ---- compute: 8 k-pairs, 8x4 micro-tile, scalar muls ----
#pragma unroll
        for (int kp = 0; kp < BK / 2; ++kp) {
            const float* rA = sAw + kp * ARS + ty * 20;
            const float* rW = sWw + kp * WRS + tx * 12;
            f32x4 A0 = *(const f32x4*)(rA + 0);
            f32x4 A1 = *(const f32x4*)(rA + 4);
            f32x4 A2 = *(const f32x4*)(rA + 8);
            f32x4 A3 = *(const f32x4*)(rA + 12);
            f32x4 W0 = *(const f32x4*)(rW + 0);
            f32x4 W1 = *(const f32x4*)(rW + 4);

            float a0[8] = {A0.x, A0.z, A1.x, A1.z, A2.x, A2.z, A3.x, A3.z};
            float a1[8] = {A0.y, A0.w, A1.y, A1.w, A2.y, A2.w, A3.y, A3.w};
            float b0[4] = {W0.x, W0.z, W1.x, W1.z};
            float b1[4] = {W0.y, W0.w, W1.y, W1.w};

#pragma unroll
            for (int i = 0; i < 8; ++i)
#pragma unroll
                for (int j = 0; j < 4; ++j) {
                    float p0 = a0[i] * b0[j];
                    float p1 = a1[i] * b1[j];
                    mam_upd(mx[i][j], mn[i][j], p0, p1);
                }
        }
    }

    // strips now dead; cmx/cmn overlap them -> drain all waves first
    __syncthreads();

    // ---- cross-wave combine: sequential merge rounds through LDS ----
    for (int rnd = 0; rnd < 4; ++rnd) {
        if (w == rnd) {
#pragma unroll
            for (int i = 0; i < 8; ++i)
#pragma unroll
                for (int j = 0; j < 4; ++j) {
                    const int idx = (ty * 8 + i) * TSN + tx * 4 + j;
                    if (rnd == 0) {
                        cmx[idx] = mx[i][j];
                        cmn[idx] = mn[i][j];
                    } else {
                        cmx[idx] = fmaxf(cmx[idx], mx[i][j]);
                        cmn[idx] = fminf(cmn[idx], mn[i][j]);
                    }
                }
        }
        __syncthreads();
    }

    // ---- bias + store: thread t -> row t>>2, col quad t&3 (8 cols) ----
    {
        const int row = t >> 2;
        const int cq  = t & 3;
        const int col = cq * 8;
        float4 blo = *(const float4*)(bias + n0 + col);
        float4 bhi = *(const float4*)(bias + n0 + col + 4);
        const int idx = row * TSN + col;
        float4 o0, o1;
        o0.x = cmx[idx + 0] + cmn[idx + 0] + blo.x;
        o0.y = cmx[idx + 1] + cmn[idx + 1] + blo.y;
        o0.z = cmx[idx + 2] + cmn[idx + 2] + blo.z;
        o0.w = cmx[idx + 3] + cmn[idx + 3] + blo.w;
        o1.x = cmx[idx + 4] + cmn[idx + 4] + bhi.x;
        o1.y = cmx[idx + 5] + cmn[idx + 5] + bhi.y;
        o1.z = cmx[idx + 6] + cmn[idx + 6] + bhi.z;
        o1.w = cmx[idx + 7] + cmn[idx + 7] + bhi.w;
        float4* p = (float4*)(C + (size_t)(m0 + row) * N + n0 + col);
        p[0] = o0;
        p[1] = o1;
    }
}

// ---- fallback (proven R2 kernel) for shapes the fast path can't take ----
#define BM 64
#define BN 64
#define FBK 32
#define LDSW 68

__device__ __forceinline__ void mam_upd_fb(float& mx, float& mn, float p0, float p1) {
    float nmx, nmn;
    asm("v_max3_f32 %0, %1, %2, %3" : "=v"(nmx) : "v"(p0), "v"(p1), "v"(mx));
    asm("v_min3_f32 %0, %1, %2, %3" : "=v"(nmn) : "v"(p0), "v"(p1), "v"(mn));
    mx = nmx;
    mn = nmn;
}

__global__ __launch_bounds__(256) void mam_fallback(
    const float* __restrict__ A, const float* __restrict__ W,
    const float* __restrict__ bias, float* __restrict__ C,
    int M, int N, int K)
{
    __shared__ float Asf[FBK][LDSW];
    __shared__ float Wsf[FBK][LDSW];

    const int t  = threadIdx.x;
    const int tx = t & 15;
    const int ty = t >> 4;
    const int m0 = blockIdx.y * BM;
    const int n0 = blockIdx.x * BN;
    const int r  = t >> 3;
    const int kq = t & 7;

    const float* Aptr = A + (size_t)(m0 + r) * K + kq * 4;
    const float* Wptr = W + (size_t)(n0 + r) * K + kq * 4;

    float vmax[4][4], vmin[4][4];
#pragma unroll
    for (int i = 0; i < 4; ++i)
#pragma unroll
        for (int j = 0; j < 4; ++j) {
            vmax[i][j] = -INFINITY;
            vmin[i][j] =  INFINITY;
        }

    for (int k0 = 0; k0 < K; k0 += FBK) {
        float4 a0 = *(const float4*)(Aptr);
        float4 a1 = *(const float4*)(Aptr + (size_t)32 * K);
        float4 w0 = *(const float4*)(Wptr);
        float4 w1 = *(const float4*)(Wptr + (size_t)32 * K);
        Aptr += FBK;
        Wptr += FBK;

        const int kk = kq * 4;
        Asf[kk + 0][r]      = a0.x;
        Asf[kk + 1][r]      = a0.y;
        Asf[kk + 2][r]      = a0.z;
        Asf[kk + 3][r]      = a0.w;
        Asf[kk + 0][r + 32] = a1.x;
        Asf[kk + 1][r + 32] = a1.y;
        Asf[kk + 2][r + 32] = a1.z;
        Asf[kk + 3][r + 32] = a1.w;

        Wsf[kk + 0][r]      = w0.x;
        Wsf[kk + 1][r]      = w0.y;
        Wsf[kk + 2][r]      = w0.z;
        Wsf[kk + 3][r]      = w0.w;
        Wsf[kk + 0][r + 32] = w1.x;
        Wsf[kk + 1][r + 32] = w1.y;
        Wsf[kk + 2][r + 32] = w1.z;
        Wsf[kk + 3][r + 32] = w1.w;

        __syncthreads();

#pragma unroll
        for (int k = 0; k < FBK; k += 2) {
            float4 ta0 = *(const float4*)&Asf[k    ][ty * 4];
            float4 ta1 = *(const float4*)&Asf[k + 1][ty * 4];
            float4 tb0 = *(const float4*)&Wsf[k    ][tx * 4];
            float4 tb1 = *(const float4*)&Wsf[k + 1][tx * 4];

            float a0v[4] = {ta0.x, ta0.y, ta0.z, ta0.w};
            float a1v[4] = {ta1.x, ta1.y, ta1.z, ta1.w};
            float b0v[4] = {tb0.x, tb0.y, tb0.z, tb0.w};
            float b1v[4] = {tb1.x, tb1.y, tb1.z, tb1.w};

#pragma unroll
            for (int i = 0; i < 4; ++i)
#pragma unroll
                for (int j = 0; j < 4; ++j) {
                    float p0 = a0v[i] * b0v[j];
                    float p1 = a1v[i] * b1v[j];
                    mam_upd_fb(vmax[i][j], vmin[i][j], p0, p1);
                }
        }
        __syncthreads();
    }

    float4 bv = *(const float4*)(bias + n0 + tx * 4);
#pragma unroll
    for (int i = 0; i < 4; ++i) {
        float4 o;
        o.x = vmax[i][0] + vmin[i][0] + bv.x;
        o.y = vmax[i][1] + vmin[i][1] + bv.y;
        o.z = vmax[i][2] + vmin[i][2] + bv.z;
        o.w = vmax[i][3] + vmin[i][3] + bv.w;
        *(float4*)(C + (size_t)(m0 + ty * 4 + i) * N + n0 + tx * 4) = o;
    }
}

extern "C" void kernel_launch(void* const* d_in, const int* in_sizes, int n_in,
                              void* d_out, int out_size, void* d_ws, size_t ws_size,
                              hipStream_t stream) {
    const float* x    = (const float*)d_in[0];
    const float* w    = (const float*)d_in[1];
    const float* bias = (const float*)d_in[2];
    float* out = (float*)d_out;

    const int N = in_sizes[2];
    const int K = in_sizes[1] / N;
    const int M = in_sizes[0] / K;

    const bool fast_ok = (K % (4 * BK) == 0) && (M % TSM == 0) && (N % TSN == 0);

    if (fast_ok) {
        dim3 grid(N / TSN, M / TSM);   // (32, 32) = 1024 blocks
        mam_sk<<<grid, 256, 0, stream>>>(x, w, bias, out, M, N, K);
    } else {
        dim3 grid(N / BN, M / BM);
        mam_fallback<<<grid, 256, 0, stream>>>(x, w, bias, out, M, N, K);
    }
}

// Round 9
// 152.823 us; speedup vs baseline: 1.1182x; 1.0253x over previous
//
#include <hip/hip_runtime.h>
#include <math.h>

// MAM dense: C[m,n] = max_k(A[m,k]*W[n,k]) + min_k(A[m,k]*W[n,k]) + bias[n]
// A: [M,K] fp32, W: [N,K] fp32 (torch layout), C: [M,N]
//
// R22 = consolidation test: R13 geometry (64x64 tile, 8x8 micro, 4-wave
// k-split) + R16/R21 conflict-free stride-20 bumped strips + R21 register
// prefetch. R21 post-mortem: prefetch recovered 112->104, but R13 (8
// waves/CU, DS 41us) and R21 (14 waves/CU, DS 69us, 1.5x DS work, 1.7x
// TLP) CONVERGE at 103-104us -> TLP and DS volume both exonerated. Common
// factor: the VALU mix (67.1M wave-instr of 2xmul+max3+min3). If
// max3/min3 (VOP3 3-src) are half-rate (4cy), pipe demand = 82us and both
// kernels sit at exactly 79% of it. This round: cleanest kernel at the
// DS-minimal 8x8 point (removes R13's 2.98M conflict-cycles ~5us).
// Decision rule: 101-104 => third-geometry convergence, VALU-mix floor
// confirmed, declare roofline next round. <95 => model wrong, iterate.

#define TS 64                // m and n tile
#define BK 16                // k per stage
#define RSF 156              // bumped row stride: 7*20 + 16 floats
#define STRIPF (8 * RSF)     // 8 kp-rows per strip = 1248 floats

typedef __attribute__((ext_vector_type(4))) float f32x4;

__device__ __forceinline__ void mam_upd(float& mx, float& mn, float p0, float p1) {
    asm("v_max3_f32 %0, %1, %2, %0" : "+v"(mx) : "v"(p0), "v"(p1));
    asm("v_min3_f32 %0, %1, %2, %0" : "+v"(mn) : "v"(p0), "v"(p1));
}

__global__
__attribute__((amdgpu_flat_work_group_size(256, 256)))
__attribute__((amdgpu_waves_per_eu(2, 4)))
void mam_sk(
    const float* __restrict__ A, const float* __restrict__ W,
    const float* __restrict__ bias, float* __restrict__ C,
    int M, int N, int K)
{
    // 4 waves x (A strip + W strip) = 8 x 1248 floats = 39936 B.
    // After the main loop (barrier) the same memory holds cmx/cmn
    // (64x64 each = 8192 floats <= 9984).
    __shared__ __align__(16) float smem[8 * STRIPF];
    float* cmx = smem;
    float* cmn = smem + TS * TS;

    const int t    = threadIdx.x;
    const int w    = t >> 6;        // wave id == k-group
    const int lane = t & 63;
    const int ty   = lane >> 3;     // m micro group (8 rows)
    const int tx   = lane & 7;      // n micro group (8 cols)
    const int m0   = blockIdx.y * TS;
    const int n0   = blockIdx.x * TS;
    const int kc   = K >> 2;        // 256 k per wave
    const int kb0  = w * kc;

    const int sr = lane >> 2;       // staging row 0..15
    const int sc = lane & 3;        // staging k-quad 0..3

    float* sAw = smem + (size_t)w * (2 * STRIPF);
    float* sWw = sAw + STRIPF;

    const float* Ap = A + (size_t)(m0 + sr) * K + kb0 + sc * 4;
    const float* Wp = W + (size_t)(n0 + sr) * K + kb0 + sc * 4;

    float mx[8][8], mn[8][8];
#pragma unroll
    for (int i = 0; i < 8; ++i)
#pragma unroll
        for (int j = 0; j < 8; ++j) {
            mx[i][j] = -INFINITY;
            mn[i][j] =  INFINITY;
        }

    // bumped pair offset for staging rows: row r -> 20*(r>>3) + 2*(r&7);
    // r = sr + 16q -> mo + 40q.
    const int mo = 20 * (sr >> 3) + 2 * (sr & 7);

    // ---- prologue: load stage 0 (8 float4 per lane) ----
    float4 ra[4], rw[4];
#pragma unroll
    for (int q = 0; q < 4; ++q) {
        ra[q] = *(const float4*)(Ap + (size_t)q * 16 * K);
        rw[q] = *(const float4*)(Wp + (size_t)q * 16 * K);
    }
    Ap += BK;
    Wp += BK;

    const int nStages = kc / BK;    // 16
    for (int s = 0; s < nStages; ++s) {
        // ---- scatter current stage (regs -> strips), k-pair interleaved
        // with stride-20 bump; float4 (k0..k3): (x,y) -> kp-row sc*2,
        // (z,w) -> kp-row sc*2+1.
        // (no barrier: strips are wave-private; same-wave DS ops ordered)
#pragma unroll
        for (int q = 0; q < 4; ++q) {
            const int po = mo + 40 * q;
            *(float2*)&sAw[(sc * 2 + 0) * RSF + po] = make_float2(ra[q].x, ra[q].y);
            *(float2*)&sAw[(sc * 2 + 1) * RSF + po] = make_float2(ra[q].z, ra[q].w);
            *(float2*)&sWw[(sc * 2 + 0) * RSF + po] = make_float2(rw[q].x, rw[q].y);
            *(float2*)&sWw[(sc * 2 + 1) * RSF + po] = make_float2(rw[q].z, rw[q].w);
        }

        // ---- issue next stage's loads BEFORE compute (T14 pipeline) ----
        if (s + 1 < nStages) {
#pragma unroll
            for (int q = 0; q < 4; ++q) {
                ra[q] = *(const float4*)(Ap + (size_t)q * 16 * K);
                rw[q] = *(const float4*)(Wp + (size_t)q * 16 * K);
            }
            Ap += BK;
            Wp += BK;
        }

        // ---- compute: 8 k-pairs, 8x8 micro-tile, scalar muls ----
#pragma unroll
        for (int kp = 0; kp < BK / 2; ++kp) {
            const float* rA = sAw + kp * RSF + ty * 20;
            const float* rW = sWw + kp * RSF + tx * 20;
            f32x4 A0 = *(const f32x4*)(rA + 0);
            f32x4 A1 = *(const f32x4*)(rA + 4);
            f32x4 A2 = *(const f32x4*)(rA + 8);
            f32x4 A3 = *(const f32x4*)(rA + 12);
            f32x4 W0 = *(const f32x4*)(rW + 0);
            f32x4 W1 = *(const f32x4*)(rW + 4);
            f32x4 W2 = *(const f32x4*)(rW + 8);
            f32x4 W3 = *(const f32x4*)(rW + 12);

            float a0[8] = {A0.x, A0.z, A1.x, A1.z, A2.x, A2.z, A3.x, A3.z};
            float a1[8] = {A0.y, A0.w, A1.y, A1.w, A2.y, A2.w, A3.y, A3.w};
            float b0[8] = {W0.x, W0.z, W1.x, W1.z, W2.x, W2.z, W3.x, W3.z};
            float b1[8] = {W0.y, W0.w, W1.y, W1.w, W2.y, W2.w, W3.y, W3.w};

#pragma unroll
            for (int i = 0; i < 8; ++i)
#pragma unroll
                for (int j = 0; j < 8; ++j) {
                    float p0 = a0[i] * b0[j];
                    float p1 = a1[i] * b1[j];
                    mam_upd(mx[i][j], mn[i][j], p0, p1);
                }
        }
    }

    // strips now dead; cmx/cmn overlap them -> drain all waves first
    __syncthreads();

    // ---- cross-wave combine: sequential merge rounds through LDS ----
    for (int rnd = 0; rnd < 4; ++rnd) {
        if (w == rnd) {
#pragma unroll
            for (int i = 0; i < 8; ++i)
#pragma unroll
                for (int j = 0; j < 8; ++j) {
                    const int idx = (ty * 8 + i) * TS + tx * 8 + j;
                    if (rnd == 0) {
                        cmx[idx] = mx[i][j];
                        cmn[idx] = mn[i][j];
                    } else {
                        cmx[idx] = fmaxf(cmx[idx], mx[i][j]);
                        cmn[idx] = fminf(cmn[idx], mn[i][j]);
                    }
                }
        }
        __syncthreads();
    }

    // ---- bias + store: wave w writes micro-rows i = {2w, 2w+1} ----
    float4 blo = *(const float4*)(bias + n0 + tx * 8);
    float4 bhi = *(const float4*)(bias + n0 + tx * 8 + 4);
#pragma unroll
    for (int i2 = 0; i2 < 2; ++i2) {
        const int i   = w * 2 + i2;
        const int row = ty * 8 + i;
        const int idx = row * TS + tx * 8;
        float4 o0, o1;
        o0.x = cmx[idx + 0] + cmn[idx + 0] + blo.x;
        o0.y = cmx[idx + 1] + cmn[idx + 1] + blo.y;
        o0.z = cmx[idx + 2] + cmn[idx + 2] + blo.z;
        o0.w = cmx[idx + 3] + cmn[idx + 3] + blo.w;
        o1.x = cmx[idx + 4] + cmn[idx + 4] + bhi.x;
        o1.y = cmx[idx + 5] + cmn[idx + 5] + bhi.y;
        o1.z = cmx[idx + 6] + cmn[idx + 6] + bhi.z;
        o1.w = cmx[idx + 7] + cmn[idx + 7] + bhi.w;
        float4* p = (float4*)(C + (size_t)(m0 + row) * N + n0 + tx * 8);
        p[0] = o0;
        p[1] = o1;
    }
}

// ---- fallback (proven R2 kernel) for shapes the fast path can't take ----
#define BM 64
#define BN 64
#define FBK 32
#define LDSW 68

__device__ __forceinline__ void mam_upd_fb(float& mx, float& mn, float p0, float p1) {
    float nmx, nmn;
    asm("v_max3_f32 %0, %1, %2, %3" : "=v"(nmx) : "v"(p0), "v"(p1), "v"(mx));
    asm("v_min3_f32 %0, %1, %2, %3" : "=v"(nmn) : "v"(p0), "v"(p1), "v"(mn));
    mx = nmx;
    mn = nmn;
}

__global__ __launch_bounds__(256) void mam_fallback(
    const float* __restrict__ A, const float* __restrict__ W,
    const float* __restrict__ bias, float* __restrict__ C,
    int M, int N, int K)
{
    __shared__ float Asf[FBK][LDSW];
    __shared__ float Wsf[FBK][LDSW];

    const int t  = threadIdx.x;
    const int tx = t & 15;
    const int ty = t >> 4;
    const int m0 = blockIdx.y * BM;
    const int n0 = blockIdx.x * BN;
    const int r  = t >> 3;
    const int kq = t & 7;

    const float* Aptr = A + (size_t)(m0 + r) * K + kq * 4;
    const float* Wptr = W + (size_t)(n0 + r) * K + kq * 4;

    float vmax[4][4], vmin[4][4];
#pragma unroll
    for (int i = 0; i < 4; ++i)
#pragma unroll
        for (int j = 0; j < 4; ++j) {
            vmax[i][j] = -INFINITY;
            vmin[i][j] =  INFINITY;
        }

    for (int k0 = 0; k0 < K; k0 += FBK) {
        float4 a0 = *(const float4*)(Aptr);
        float4 a1 = *(const float4*)(Aptr + (size_t)32 * K);
        float4 w0 = *(const float4*)(Wptr);
        float4 w1 = *(const float4*)(Wptr + (size_t)32 * K);
        Aptr += FBK;
        Wptr += FBK;

        const int kk = kq * 4;
        Asf[kk + 0][r]      = a0.x;
        Asf[kk + 1][r]      = a0.y;
        Asf[kk + 2][r]      = a0.z;
        Asf[kk + 3][r]      = a0.w;
        Asf[kk + 0][r + 32] = a1.x;
        Asf[kk + 1][r + 32] = a1.y;
        Asf[kk + 2][r + 32] = a1.z;
        Asf[kk + 3][r + 32] = a1.w;

        Wsf[kk + 0][r]      = w0.x;
        Wsf[kk + 1][r]      = w0.y;
        Wsf[kk + 2][r]      = w0.z;
        Wsf[kk + 3][r]      = w0.w;
        Wsf[kk + 0][r + 32] = w1.x;
        Wsf[kk + 1][r + 32] = w1.y;
        Wsf[kk + 2][r + 32] = w1.z;
        Wsf[kk + 3][r + 32] = w1.w;

        __syncthreads();

#pragma unroll
        for (int k = 0; k < FBK; k += 2) {
            float4 ta0 = *(const float4*)&Asf[k    ][ty * 4];
            float4 ta1 = *(const float4*)&Asf[k + 1][ty * 4];
            float4 tb0 = *(const float4*)&Wsf[k    ][tx * 4];
            float4 tb1 = *(const float4*)&Wsf[k + 1][tx * 4];

            float a0v[4] = {ta0.x, ta0.y, ta0.z, ta0.w};
            float a1v[4] = {ta1.x, ta1.y, ta1.z, ta1.w};
            float b0v[4] = {tb0.x, tb0.y, tb0.z, tb0.w};
            float b1v[4] = {tb1.x, tb1.y, tb1.z, tb1.w};

#pragma unroll
            for (int i = 0; i < 4; ++i)
#pragma unroll
                for (int j = 0; j < 4; ++j) {
                    float p0 = a0v[i] * b0v[j];
                    float p1 = a1v[i] * b1v[j];
                    mam_upd_fb(vmax[i][j], vmin[i][j], p0, p1);
                }
        }
        __syncthreads();
    }

    float4 bv = *(const float4*)(bias + n0 + tx * 4);
#pragma unroll
    for (int i = 0; i < 4; ++i) {
        float4 o;
        o.x = vmax[i][0] + vmin[i][0] + bv.x;
        o.y = vmax[i][1] + vmin[i][1] + bv.y;
        o.z = vmax[i][2] + vmin[i][2] + bv.z;
        o.w = vmax[i][3] + vmin[i][3] + bv.w;
        *(float4*)(C + (size_t)(m0 + ty * 4 + i) * N + n0 + tx * 4) = o;
    }
}

extern "C" void kernel_launch(void* const* d_in, const int* in_sizes, int n_in,
                              void* d_out, int out_size, void* d_ws, size_t ws_size,
                              hipStream_t stream) {
    const float* x    = (const float*)d_in[0];
    const float* w    = (const float*)d_in[1];
    const float* bias = (const float*)d_in[2];
    float* out = (float*)d_out;

    const int N = in_sizes[2];
    const int K = in_sizes[1] / N;
    const int M = in_sizes[0] / K;

    const bool fast_ok = (K % (4 * BK) == 0) && (M % TS == 0) && (N % TS == 0);

    if (fast_ok) {
        dim3 grid(N / TS, M / TS);   // (16, 32) = 512 blocks
        mam_sk<<<grid, 256, 0, stream>>>(x, w, bias, out, M, N, K);
    } else {
        dim3 grid(N / BN, M / BM);
        mam_fallback<<<grid, 256, 0, stream>>>(x, w, bias, out, M, N, K);
    }
}